// Round 1
// baseline (388.527 us; speedup 1.0000x reference)
//
#include <hip/hip_runtime.h>
#include <hip/hip_bf16.h>
#include <cstdint>
#include <cstddef>

// Problem shape (fixed): x [B=16][N=2048][D=512] fp32
#define BB 16
#define NN 2048
#define DD 512

typedef _Float16 f16x8 __attribute__((ext_vector_type(8)));
typedef _Float16 f16x4 __attribute__((ext_vector_type(4)));
typedef float f32x4 __attribute__((ext_vector_type(4)));

// ---------------------------------------------------------------------------
// K1a: per-row inverse L2 norm (fp32 exact), cast x -> fp16, zero denom.
// One wave per row. 512 elems = 64 lanes x 8 floats.
// ---------------------------------------------------------------------------
__global__ __launch_bounds__(64) void k_prep_rows(const float* __restrict__ x,
                                                  _Float16* __restrict__ xh,
                                                  float* __restrict__ rnorm,
                                                  float* __restrict__ denom) {
    const int row = blockIdx.x;          // 0 .. B*N-1
    const int lane = threadIdx.x;        // 0 .. 63
    const float* xr = x + (size_t)row * DD;
    float4 a = ((const float4*)xr)[lane];
    float4 b = ((const float4*)xr)[lane + 64];
    float ss = a.x*a.x + a.y*a.y + a.z*a.z + a.w*a.w
             + b.x*b.x + b.y*b.y + b.z*b.z + b.w*b.w;
    #pragma unroll
    for (int o = 1; o < 64; o <<= 1) ss += __shfl_xor(ss, o);
    if (lane == 0) {
        rnorm[row] = 1.0f / sqrtf(ss);
        denom[row] = 0.0f;
    }
    _Float16* dst = xh + (size_t)row * DD;
    f16x4 v0 = {(_Float16)a.x, (_Float16)a.y, (_Float16)a.z, (_Float16)a.w};
    f16x4 v1 = {(_Float16)b.x, (_Float16)b.y, (_Float16)b.z, (_Float16)b.w};
    *(f16x4*)(dst + 4 * lane) = v0;
    *(f16x4*)(dst + 256 + 4 * lane) = v1;
}

// ---------------------------------------------------------------------------
// K1b: transpose-cast x -> vT fp16, vT[b][d][j].  64x64 tiles via LDS.
// grid (N/64, D/64, B), 256 threads.
// ---------------------------------------------------------------------------
__global__ __launch_bounds__(256) void k_transpose(const float* __restrict__ x,
                                                   _Float16* __restrict__ vT) {
    __shared__ _Float16 t[64 * 72];      // [d][j], row stride 72 halves (16B aligned, bank-spread)
    const int tid = threadIdx.x;
    const int b = blockIdx.z;
    const int j0 = blockIdx.x * 64, d0 = blockIdx.y * 64;
    const float* xb = x + (size_t)b * NN * DD;
    #pragma unroll
    for (int p = 0; p < 4; ++p) {
        const int r = p * 16 + (tid >> 4);      // j within tile
        const int c = (tid & 15) * 4;           // d within tile
        float4 v = *(const float4*)(xb + (size_t)(j0 + r) * DD + d0 + c);
        t[(c + 0) * 72 + r] = (_Float16)v.x;
        t[(c + 1) * 72 + r] = (_Float16)v.y;
        t[(c + 2) * 72 + r] = (_Float16)v.z;
        t[(c + 3) * 72 + r] = (_Float16)v.w;
    }
    __syncthreads();
    #pragma unroll
    for (int p = 0; p < 2; ++p) {
        const int id = p * 256 + tid;
        const int dr = id >> 3;                 // d row within tile
        const int ch = (id & 7) * 8;            // j chunk (8 halves = 16B)
        *(uint4*)(vT + ((size_t)b * DD + d0 + dr) * NN + j0 + ch) =
            *(const uint4*)&t[dr * 72 + ch];
    }
}

// ---------------------------------------------------------------------------
// K2: W = exp( (Xh Xh^T) * rn_i * rn_j ) tile GEMM, fp16 MFMA 16x16x32.
// 128x128 C-tile, 4 waves each 64x64 (4x4 grid of 16x16), BK=64.
// Epilogue: exp -> LDS tile -> coalesced global store; row sums -> atomic denom.
// grid (N/128, N/128, B), 256 threads.
// ---------------------------------------------------------------------------
__global__ __launch_bounds__(256) void k_scores(const _Float16* __restrict__ xh,
                                                const float* __restrict__ rnorm,
                                                _Float16* __restrict__ W,
                                                float* __restrict__ denom) {
    __shared__ _Float16 smem[2 * 128 * 72];   // As,Bs ; reused as Wt[128][136] in epilogue
    __shared__ float rnI[128], rnJ[128];
    const int tid = threadIdx.x;
    const int lane = tid & 63, wv = tid >> 6;
    const int wr = wv >> 1, wc = wv & 1;
    const int m_ = lane & 15, quad = lane >> 4;
    const int b = blockIdx.z;
    const int I = blockIdx.x * 128, J = blockIdx.y * 128;
    const _Float16* Ab = xh + ((size_t)b * NN + I) * DD;
    const _Float16* Bb = xh + ((size_t)b * NN + J) * DD;
    if (tid < 128) rnI[tid] = rnorm[b * NN + I + tid];
    else           rnJ[tid - 128] = rnorm[b * NN + J + (tid - 128)];

    f32x4 acc[4][4];
    #pragma unroll
    for (int i = 0; i < 4; ++i)
        #pragma unroll
        for (int j = 0; j < 4; ++j) acc[i][j] = (f32x4){0.f, 0.f, 0.f, 0.f};

    _Float16* As = smem;
    _Float16* Bs = smem + 128 * 72;
    for (int kb = 0; kb < DD / 64; ++kb) {
        const int k0 = kb * 64;
        #pragma unroll
        for (int p = 0; p < 4; ++p) {
            const int id = p * 256 + tid;
            const int r = id >> 3;              // tile row
            const int ch = (id & 7) * 8;        // k chunk (8 halves = 16B)
            *(uint4*)&As[r * 72 + ch] = *(const uint4*)(Ab + (size_t)r * DD + k0 + ch);
            *(uint4*)&Bs[r * 72 + ch] = *(const uint4*)(Bb + (size_t)r * DD + k0 + ch);
        }
        __syncthreads();
        #pragma unroll
        for (int kc = 0; kc < 2; ++kc) {
            const int ko = kc * 32 + quad * 8;
            f16x8 af[4], bf[4];
            #pragma unroll
            for (int t = 0; t < 4; ++t) {
                af[t] = *(const f16x8*)&As[(wr * 64 + t * 16 + m_) * 72 + ko];
                bf[t] = *(const f16x8*)&Bs[(wc * 64 + t * 16 + m_) * 72 + ko];
            }
            #pragma unroll
            for (int i = 0; i < 4; ++i)
                #pragma unroll
                for (int j = 0; j < 4; ++j)
                    acc[i][j] = __builtin_amdgcn_mfma_f32_16x16x32_f16(af[i], bf[j], acc[i][j], 0, 0, 0);
        }
        __syncthreads();
    }

    // Epilogue: scale + exp, scatter into LDS W-tile [128][136]
    _Float16* Wt = smem;
    #pragma unroll
    for (int i = 0; i < 4; ++i) {
        const int rowb = wr * 64 + i * 16 + quad * 4;
        #pragma unroll
        for (int j = 0; j < 4; ++j) {
            const int col = wc * 64 + j * 16 + m_;
            const float rj = rnJ[col];
            #pragma unroll
            for (int r = 0; r < 4; ++r) {
                const float sv = acc[i][j][r] * rnI[rowb + r] * rj;
                Wt[(rowb + r) * 136 + col] = (_Float16)__expf(sv);
            }
        }
    }
    __syncthreads();

    // Row sums of the quantized W (keeps numerator/denominator consistent)
    {
        const int rr = tid >> 1, half = tid & 1;
        const _Float16* wp = &Wt[rr * 136 + half * 64];
        float s = 0.f;
        #pragma unroll
        for (int c = 0; c < 64; c += 8) {
            f16x8 v = *(const f16x8*)&wp[c];
            #pragma unroll
            for (int k = 0; k < 8; ++k) s += (float)v[k];
        }
        s += __shfl_xor(s, 1);
        if (half == 0) atomicAdd(&denom[b * NN + I + rr], s);
    }
    // Coalesced store of W tile
    {
        const int rr = tid >> 1, off = (tid & 1) * 64;
        _Float16* wg = W + ((size_t)b * NN + I + rr) * NN + J + off;
        const _Float16* wl = &Wt[rr * 136 + off];
        #pragma unroll
        for (int c = 0; c < 64; c += 8)
            *(uint4*)(wg + c) = *(const uint4*)(wl + c);
    }
}

// ---------------------------------------------------------------------------
// K3: O = (W @ V) * (1/denom_i), fp32 out.  A=W [i][j] (k=j contig),
// B=vT [d][j] (k=j contig). Same GEMM structure, K=2048.
// grid (N/128, D/128, B), 256 threads.
// ---------------------------------------------------------------------------
__global__ __launch_bounds__(256) void k_pv(const _Float16* __restrict__ W,
                                            const _Float16* __restrict__ vT,
                                            const float* __restrict__ denom,
                                            float* __restrict__ out) {
    __shared__ _Float16 smem[2 * 128 * 72];
    __shared__ float rdI[128];
    const int tid = threadIdx.x;
    const int lane = tid & 63, wv = tid >> 6;
    const int wr = wv >> 1, wc = wv & 1;
    const int m_ = lane & 15, quad = lane >> 4;
    const int b = blockIdx.z;
    const int I = blockIdx.x * 128;     // i tile
    const int D0 = blockIdx.y * 128;    // d tile
    const _Float16* Ab = W + ((size_t)b * NN + I) * NN;
    const _Float16* Bb = vT + ((size_t)b * DD + D0) * NN;
    if (tid < 128) rdI[tid] = 1.0f / denom[b * NN + I + tid];

    f32x4 acc[4][4];
    #pragma unroll
    for (int i = 0; i < 4; ++i)
        #pragma unroll
        for (int j = 0; j < 4; ++j) acc[i][j] = (f32x4){0.f, 0.f, 0.f, 0.f};

    _Float16* As = smem;
    _Float16* Bs = smem + 128 * 72;
    for (int kb = 0; kb < NN / 64; ++kb) {
        const int k0 = kb * 64;
        #pragma unroll
        for (int p = 0; p < 4; ++p) {
            const int id = p * 256 + tid;
            const int r = id >> 3;
            const int ch = (id & 7) * 8;
            *(uint4*)&As[r * 72 + ch] = *(const uint4*)(Ab + (size_t)r * NN + k0 + ch);
            *(uint4*)&Bs[r * 72 + ch] = *(const uint4*)(Bb + (size_t)r * NN + k0 + ch);
        }
        __syncthreads();
        #pragma unroll
        for (int kc = 0; kc < 2; ++kc) {
            const int ko = kc * 32 + quad * 8;
            f16x8 af[4], bf[4];
            #pragma unroll
            for (int t = 0; t < 4; ++t) {
                af[t] = *(const f16x8*)&As[(wr * 64 + t * 16 + m_) * 72 + ko];
                bf[t] = *(const f16x8*)&Bs[(wc * 64 + t * 16 + m_) * 72 + ko];
            }
            #pragma unroll
            for (int i = 0; i < 4; ++i)
                #pragma unroll
                for (int j = 0; j < 4; ++j)
                    acc[i][j] = __builtin_amdgcn_mfma_f32_16x16x32_f16(af[i], bf[j], acc[i][j], 0, 0, 0);
        }
        __syncthreads();
    }

    // Epilogue: scale by 1/denom and store fp32
    #pragma unroll
    for (int i = 0; i < 4; ++i) {
        const int rowb = wr * 64 + i * 16 + quad * 4;
        #pragma unroll
        for (int r = 0; r < 4; ++r) {
            const float sc = rdI[rowb + r];
            float* op = out + ((size_t)b * NN + I + rowb + r) * DD + D0;
            #pragma unroll
            for (int j = 0; j < 4; ++j)
                op[wc * 64 + j * 16 + m_] = acc[i][j][r] * sc;
        }
    }
}

// ---------------------------------------------------------------------------
extern "C" void kernel_launch(void* const* d_in, const int* in_sizes, int n_in,
                              void* d_out, int out_size, void* d_ws, size_t ws_size,
                              hipStream_t stream) {
    const float* x = (const float*)d_in[0];
    char* ws = (char*)d_ws;
    // Workspace layout (192.25 MiB total):
    _Float16* xh    = (_Float16*)(ws);                        // 32 MiB  fp16 x
    _Float16* vT    = (_Float16*)(ws + (size_t)33554432);     // 32 MiB  fp16 x^T per batch
    _Float16* W     = (_Float16*)(ws + (size_t)67108864);     // 128 MiB fp16 exp-scores
    float*    rnorm = (float*)   (ws + (size_t)201326592);    // 128 KiB
    float*    denom = (float*)   (ws + (size_t)201457664);    // 128 KiB
    float*    out   = (float*)d_out;

    k_prep_rows<<<BB * NN, 64, 0, stream>>>(x, xh, rnorm, denom);
    k_transpose<<<dim3(NN / 64, DD / 64, BB), 256, 0, stream>>>(x, vT);
    k_scores<<<dim3(NN / 128, NN / 128, BB), 256, 0, stream>>>(xh, rnorm, W, denom);
    k_pv<<<dim3(NN / 128, DD / 128, BB), 256, 0, stream>>>(W, vT, denom, out);
}

// Round 2
// 357.337 us; speedup vs baseline: 1.0873x; 1.0873x over previous
//
#include <hip/hip_runtime.h>
#include <hip/hip_bf16.h>
#include <cstdint>
#include <cstddef>

// Problem shape (fixed): x [B=16][N=2048][D=512] fp32
#define BB 16
#define NN 2048
#define DD 512

typedef _Float16 f16x8 __attribute__((ext_vector_type(8)));
typedef _Float16 f16x4 __attribute__((ext_vector_type(4)));
typedef float f32x4 __attribute__((ext_vector_type(4)));

// ---------------------------------------------------------------------------
// K1a: per-row inverse L2 norm (fp32 exact), cast x -> fp16, zero denom.
// One wave per row. 512 elems = 64 lanes x 8 floats.
// ---------------------------------------------------------------------------
__global__ __launch_bounds__(64) void k_prep_rows(const float* __restrict__ x,
                                                  _Float16* __restrict__ xh,
                                                  float* __restrict__ rnorm,
                                                  float* __restrict__ denom) {
    const int row = blockIdx.x;          // 0 .. B*N-1
    const int lane = threadIdx.x;        // 0 .. 63
    const float* xr = x + (size_t)row * DD;
    float4 a = ((const float4*)xr)[lane];
    float4 b = ((const float4*)xr)[lane + 64];
    float ss = a.x*a.x + a.y*a.y + a.z*a.z + a.w*a.w
             + b.x*b.x + b.y*b.y + b.z*b.z + b.w*b.w;
    #pragma unroll
    for (int o = 1; o < 64; o <<= 1) ss += __shfl_xor(ss, o);
    if (lane == 0) {
        rnorm[row] = 1.0f / sqrtf(ss);
        denom[row] = 0.0f;
    }
    _Float16* dst = xh + (size_t)row * DD;
    f16x4 v0 = {(_Float16)a.x, (_Float16)a.y, (_Float16)a.z, (_Float16)a.w};
    f16x4 v1 = {(_Float16)b.x, (_Float16)b.y, (_Float16)b.z, (_Float16)b.w};
    *(f16x4*)(dst + 4 * lane) = v0;
    *(f16x4*)(dst + 256 + 4 * lane) = v1;
}

// ---------------------------------------------------------------------------
// K1b: transpose-cast x -> vT fp16, vT[b][d][j].  64x64 tiles via LDS.
// grid (N/64, D/64, B), 256 threads.
// ---------------------------------------------------------------------------
__global__ __launch_bounds__(256) void k_transpose(const float* __restrict__ x,
                                                   _Float16* __restrict__ vT) {
    __shared__ _Float16 t[64 * 72];      // [d][j], row stride 72 halves
    const int tid = threadIdx.x;
    const int b = blockIdx.z;
    const int j0 = blockIdx.x * 64, d0 = blockIdx.y * 64;
    const float* xb = x + (size_t)b * NN * DD;
    #pragma unroll
    for (int p = 0; p < 4; ++p) {
        const int r = p * 16 + (tid >> 4);      // j within tile
        const int c = (tid & 15) * 4;           // d within tile
        float4 v = *(const float4*)(xb + (size_t)(j0 + r) * DD + d0 + c);
        t[(c + 0) * 72 + r] = (_Float16)v.x;
        t[(c + 1) * 72 + r] = (_Float16)v.y;
        t[(c + 2) * 72 + r] = (_Float16)v.z;
        t[(c + 3) * 72 + r] = (_Float16)v.w;
    }
    __syncthreads();
    #pragma unroll
    for (int p = 0; p < 2; ++p) {
        const int id = p * 256 + tid;
        const int dr = id >> 3;                 // d row within tile
        const int ch = (id & 7) * 8;            // j chunk (8 halves = 16B)
        *(uint4*)(vT + ((size_t)b * DD + d0 + dr) * NN + j0 + ch) =
            *(const uint4*)&t[dr * 72 + ch];
    }
}

// ---------------------------------------------------------------------------
// K2: W = exp( (Xh Xh^T) * rn_i * rn_j ), SYMMETRIC: only upper-triangular
// tile pairs (ti<=tj) are computed; off-diagonal tiles are written to both
// (I,J) and (J,I). Row sums AND col sums accumulated into denom via
// register butterflies (no LDS re-read).
// grid (136 pairs, 1, B), 256 threads. 128x128 C-tile, 4 waves, BK=64.
// ---------------------------------------------------------------------------
__global__ __launch_bounds__(256) void k_scores(const _Float16* __restrict__ xh,
                                                const float* __restrict__ rnorm,
                                                _Float16* __restrict__ W,
                                                float* __restrict__ denom) {
    __shared__ _Float16 smem[2 * 128 * 72];   // As,Bs ; reused as Wt[128][136]
    __shared__ float rnI[128], rnJ[128];
    const int tid = threadIdx.x;
    const int lane = tid & 63, wv = tid >> 6;
    const int wr = wv >> 1, wc = wv & 1;
    const int m_ = lane & 15, quad = lane >> 4;
    const int b = blockIdx.z;

    // decode triangular tile pair (ti <= tj), 16 tiles per side -> 136 pairs
    int rem = blockIdx.x, ti = 0, rowlen = NN / 128;
    while (rem >= rowlen) { rem -= rowlen; ++ti; --rowlen; }
    const int tj = ti + rem;
    const int I = ti * 128, J = tj * 128;
    const bool diag = (ti == tj);

    const _Float16* Ab = xh + ((size_t)b * NN + I) * DD;
    const _Float16* Bb = xh + ((size_t)b * NN + J) * DD;
    if (tid < 128) rnI[tid] = rnorm[b * NN + I + tid];
    else           rnJ[tid - 128] = rnorm[b * NN + J + (tid - 128)];

    f32x4 acc[4][4];
    #pragma unroll
    for (int i = 0; i < 4; ++i)
        #pragma unroll
        for (int j = 0; j < 4; ++j) acc[i][j] = (f32x4){0.f, 0.f, 0.f, 0.f};

    _Float16* As = smem;
    _Float16* Bs = smem + 128 * 72;
    for (int kb = 0; kb < DD / 64; ++kb) {
        const int k0 = kb * 64;
        #pragma unroll
        for (int p = 0; p < 4; ++p) {
            const int id = p * 256 + tid;
            const int r = id >> 3;              // tile row
            const int ch = (id & 7) * 8;        // k chunk (8 halves = 16B)
            *(uint4*)&As[r * 72 + ch] = *(const uint4*)(Ab + (size_t)r * DD + k0 + ch);
            *(uint4*)&Bs[r * 72 + ch] = *(const uint4*)(Bb + (size_t)r * DD + k0 + ch);
        }
        __syncthreads();
        #pragma unroll
        for (int kc = 0; kc < 2; ++kc) {
            const int ko = kc * 32 + quad * 8;
            f16x8 af[4], bf[4];
            #pragma unroll
            for (int t = 0; t < 4; ++t) {
                af[t] = *(const f16x8*)&As[(wr * 64 + t * 16 + m_) * 72 + ko];
                bf[t] = *(const f16x8*)&Bs[(wc * 64 + t * 16 + m_) * 72 + ko];
            }
            #pragma unroll
            for (int i = 0; i < 4; ++i)
                #pragma unroll
                for (int j = 0; j < 4; ++j)
                    acc[i][j] = __builtin_amdgcn_mfma_f32_16x16x32_f16(af[i], bf[j], acc[i][j], 0, 0, 0);
        }
        __syncthreads();
    }

    // Epilogue: scale + exp -> Wt scatter; register row/col partial sums.
    _Float16* Wt = smem;
    float rowpart[4][4];                      // [i][r]
    float colpart[4] = {0.f, 0.f, 0.f, 0.f};  // [j]
    #pragma unroll
    for (int i = 0; i < 4; ++i)
        #pragma unroll
        for (int r = 0; r < 4; ++r) rowpart[i][r] = 0.f;

    #pragma unroll
    for (int i = 0; i < 4; ++i) {
        const int rowb = wr * 64 + i * 16 + quad * 4;
        #pragma unroll
        for (int j = 0; j < 4; ++j) {
            const int col = wc * 64 + j * 16 + m_;
            const float rj = rnJ[col];
            #pragma unroll
            for (int r = 0; r < 4; ++r) {
                const float w = __expf(acc[i][j][r] * rnI[rowb + r] * rj);
                Wt[(rowb + r) * 136 + col] = (_Float16)w;
                rowpart[i][r] += w;
                colpart[j] += w;
            }
        }
    }

    // Row sums: reduce across m_ lanes (bits 0..3), one atomic per (i,r).
    #pragma unroll
    for (int i = 0; i < 4; ++i) {
        #pragma unroll
        for (int r = 0; r < 4; ++r) {
            float s = rowpart[i][r];
            s += __shfl_xor(s, 1);
            s += __shfl_xor(s, 2);
            s += __shfl_xor(s, 4);
            s += __shfl_xor(s, 8);
            if (m_ == 0)
                atomicAdd(&denom[b * NN + I + wr * 64 + i * 16 + quad * 4 + r], s);
        }
    }
    // Col sums (off-diagonal only): reduce across quad lanes (bits 4..5).
    if (!diag) {
        #pragma unroll
        for (int j = 0; j < 4; ++j) {
            float s = colpart[j];
            s += __shfl_xor(s, 16);
            s += __shfl_xor(s, 32);
            if (quad == 0)
                atomicAdd(&denom[b * NN + J + wc * 64 + j * 16 + m_], s);
        }
    }
    __syncthreads();

    // Coalesced store of W(I,J) tile
    {
        const int rr = tid >> 1, off = (tid & 1) * 64;
        _Float16* wg = W + ((size_t)b * NN + I + rr) * NN + J + off;
        const _Float16* wl = &Wt[rr * 136 + off];
        #pragma unroll
        for (int c = 0; c < 64; c += 8)
            *(uint4*)(wg + c) = *(const uint4*)(wl + c);
    }
    // Transposed store of W(J,I) tile (gather columns from Wt)
    if (!diag) {
        const int c = tid >> 1;                 // tile col = W(J,I) row
        const int h = tid & 1;                  // which half of the 128 rows
        _Float16* wg = W + ((size_t)b * NN + J + c) * NN + I + h * 64;
        #pragma unroll
        for (int g = 0; g < 8; ++g) {
            f16x8 v;
            #pragma unroll
            for (int k = 0; k < 8; ++k)
                v[k] = Wt[(h * 64 + g * 8 + k) * 136 + c];
            *(uint4*)(wg + g * 8) = *(const uint4*)&v;
        }
    }
}

// ---------------------------------------------------------------------------
// K3: O = (W @ V) * (1/denom_i), fp32 out.  A=W [i][j] (k=j contig),
// B=vT [d][j] (k=j contig). Same GEMM structure, K=2048.
// grid (N/128, D/128, B), 256 threads.
// ---------------------------------------------------------------------------
__global__ __launch_bounds__(256) void k_pv(const _Float16* __restrict__ W,
                                            const _Float16* __restrict__ vT,
                                            const float* __restrict__ denom,
                                            float* __restrict__ out) {
    __shared__ _Float16 smem[2 * 128 * 72];
    __shared__ float rdI[128];
    const int tid = threadIdx.x;
    const int lane = tid & 63, wv = tid >> 6;
    const int wr = wv >> 1, wc = wv & 1;
    const int m_ = lane & 15, quad = lane >> 4;
    const int b = blockIdx.z;
    const int I = blockIdx.x * 128;     // i tile
    const int D0 = blockIdx.y * 128;    // d tile
    const _Float16* Ab = W + ((size_t)b * NN + I) * NN;
    const _Float16* Bb = vT + ((size_t)b * DD + D0) * NN;
    if (tid < 128) rdI[tid] = 1.0f / denom[b * NN + I + tid];

    f32x4 acc[4][4];
    #pragma unroll
    for (int i = 0; i < 4; ++i)
        #pragma unroll
        for (int j = 0; j < 4; ++j) acc[i][j] = (f32x4){0.f, 0.f, 0.f, 0.f};

    _Float16* As = smem;
    _Float16* Bs = smem + 128 * 72;
    for (int kb = 0; kb < NN / 64; ++kb) {
        const int k0 = kb * 64;
        #pragma unroll
        for (int p = 0; p < 4; ++p) {
            const int id = p * 256 + tid;
            const int r = id >> 3;
            const int ch = (id & 7) * 8;
            *(uint4*)&As[r * 72 + ch] = *(const uint4*)(Ab + (size_t)r * NN + k0 + ch);
            *(uint4*)&Bs[r * 72 + ch] = *(const uint4*)(Bb + (size_t)r * NN + k0 + ch);
        }
        __syncthreads();
        #pragma unroll
        for (int kc = 0; kc < 2; ++kc) {
            const int ko = kc * 32 + quad * 8;
            f16x8 af[4], bf[4];
            #pragma unroll
            for (int t = 0; t < 4; ++t) {
                af[t] = *(const f16x8*)&As[(wr * 64 + t * 16 + m_) * 72 + ko];
                bf[t] = *(const f16x8*)&Bs[(wc * 64 + t * 16 + m_) * 72 + ko];
            }
            #pragma unroll
            for (int i = 0; i < 4; ++i)
                #pragma unroll
                for (int j = 0; j < 4; ++j)
                    acc[i][j] = __builtin_amdgcn_mfma_f32_16x16x32_f16(af[i], bf[j], acc[i][j], 0, 0, 0);
        }
        __syncthreads();
    }

    // Epilogue: scale by 1/denom and store fp32
    #pragma unroll
    for (int i = 0; i < 4; ++i) {
        const int rowb = wr * 64 + i * 16 + quad * 4;
        #pragma unroll
        for (int r = 0; r < 4; ++r) {
            const float sc = rdI[rowb + r];
            float* op = out + ((size_t)b * NN + I + rowb + r) * DD + D0;
            #pragma unroll
            for (int j = 0; j < 4; ++j)
                op[wc * 64 + j * 16 + m_] = acc[i][j][r] * sc;
        }
    }
}

// ---------------------------------------------------------------------------
extern "C" void kernel_launch(void* const* d_in, const int* in_sizes, int n_in,
                              void* d_out, int out_size, void* d_ws, size_t ws_size,
                              hipStream_t stream) {
    const float* x = (const float*)d_in[0];
    char* ws = (char*)d_ws;
    _Float16* xh    = (_Float16*)(ws);                        // 32 MiB  fp16 x
    _Float16* vT    = (_Float16*)(ws + (size_t)33554432);     // 32 MiB  fp16 x^T per batch
    _Float16* W     = (_Float16*)(ws + (size_t)67108864);     // 128 MiB fp16 exp-scores
    float*    rnorm = (float*)   (ws + (size_t)201326592);    // 128 KiB
    float*    denom = (float*)   (ws + (size_t)201457664);    // 128 KiB
    float*    out   = (float*)d_out;

    k_prep_rows<<<BB * NN, 64, 0, stream>>>(x, xh, rnorm, denom);
    k_transpose<<<dim3(NN / 64, DD / 64, BB), 256, 0, stream>>>(x, vT);
    const int npairs = (NN / 128) * (NN / 128 + 1) / 2;   // 136
    k_scores<<<dim3(npairs, 1, BB), 256, 0, stream>>>(xh, rnorm, W, denom);
    k_pv<<<dim3(NN / 128, DD / 128, BB), 256, 0, stream>>>(W, vT, denom, out);
}

// Round 3
// 354.735 us; speedup vs baseline: 1.0953x; 1.0073x over previous
//
#include <hip/hip_runtime.h>
#include <hip/hip_bf16.h>
#include <cstdint>
#include <cstddef>

// Problem shape (fixed): x [B=16][N=2048][D=512] fp32
#define BB 16
#define NN 2048
#define DD 512

typedef _Float16 f16x8 __attribute__((ext_vector_type(8)));
typedef _Float16 f16x4 __attribute__((ext_vector_type(4)));
typedef float f32x4 __attribute__((ext_vector_type(4)));

// Async global->LDS, 16 B per lane. LDS dest = wave-uniform base + lane*16.
__device__ __forceinline__ void async_ld16(void* lds, const void* g) {
    __builtin_amdgcn_global_load_lds(
        (const __attribute__((address_space(1))) unsigned int*)(uintptr_t)g,
        (__attribute__((address_space(3))) unsigned int*)(uint32_t)(uintptr_t)lds,
        16, 0, 0);
}

// ---------------------------------------------------------------------------
// K1a: per-row inverse L2 norm (fp32 exact), cast x -> fp16, zero denom.
// 256 threads = 4 waves, one row per wave.
// ---------------------------------------------------------------------------
__global__ __launch_bounds__(256) void k_prep_rows(const float* __restrict__ x,
                                                   _Float16* __restrict__ xh,
                                                   float* __restrict__ rnorm,
                                                   float* __restrict__ denom) {
    const int row = blockIdx.x * 4 + (threadIdx.x >> 6);
    const int lane = threadIdx.x & 63;
    const float* xr = x + (size_t)row * DD;
    float4 a = ((const float4*)xr)[lane];
    float4 b = ((const float4*)xr)[lane + 64];
    float ss = a.x*a.x + a.y*a.y + a.z*a.z + a.w*a.w
             + b.x*b.x + b.y*b.y + b.z*b.z + b.w*b.w;
    #pragma unroll
    for (int o = 1; o < 64; o <<= 1) ss += __shfl_xor(ss, o);
    if (lane == 0) {
        rnorm[row] = 1.0f / sqrtf(ss);
        denom[row] = 0.0f;
    }
    _Float16* dst = xh + (size_t)row * DD;
    f16x4 v0 = {(_Float16)a.x, (_Float16)a.y, (_Float16)a.z, (_Float16)a.w};
    f16x4 v1 = {(_Float16)b.x, (_Float16)b.y, (_Float16)b.z, (_Float16)b.w};
    *(f16x4*)(dst + 4 * lane) = v0;
    *(f16x4*)(dst + 256 + 4 * lane) = v1;
}

// ---------------------------------------------------------------------------
// K1b: transpose-cast x -> vT fp16, vT[b][d][j].  64x64 tiles via LDS.
// ---------------------------------------------------------------------------
__global__ __launch_bounds__(256) void k_transpose(const float* __restrict__ x,
                                                   _Float16* __restrict__ vT) {
    __shared__ _Float16 t[64 * 72];
    const int tid = threadIdx.x;
    const int b = blockIdx.z;
    const int j0 = blockIdx.x * 64, d0 = blockIdx.y * 64;
    const float* xb = x + (size_t)b * NN * DD;
    #pragma unroll
    for (int p = 0; p < 4; ++p) {
        const int r = p * 16 + (tid >> 4);
        const int c = (tid & 15) * 4;
        float4 v = *(const float4*)(xb + (size_t)(j0 + r) * DD + d0 + c);
        t[(c + 0) * 72 + r] = (_Float16)v.x;
        t[(c + 1) * 72 + r] = (_Float16)v.y;
        t[(c + 2) * 72 + r] = (_Float16)v.z;
        t[(c + 3) * 72 + r] = (_Float16)v.w;
    }
    __syncthreads();
    #pragma unroll
    for (int p = 0; p < 2; ++p) {
        const int id = p * 256 + tid;
        const int dr = id >> 3;
        const int ch = (id & 7) * 8;
        *(uint4*)(vT + ((size_t)b * DD + d0 + dr) * NN + j0 + ch) =
            *(const uint4*)&t[dr * 72 + ch];
    }
}

// ---------------------------------------------------------------------------
// K2: W = exp( (Xh Xh^T) * rn_i * rn_j ), symmetric-triangular.
// Staging: async global_load_lds (16 B/lane) into [128][64] tiles, XOR-swizzled
// at the SOURCE address (LDS(row,c) = global(row, c ^ (row&7))).
// grid (136 pairs, 1, B), 256 threads. 128x128 C-tile, 4 waves, BK=64.
// ---------------------------------------------------------------------------
__global__ __launch_bounds__(256) void k_scores(const _Float16* __restrict__ xh,
                                                const float* __restrict__ rnorm,
                                                _Float16* __restrict__ W,
                                                float* __restrict__ denom) {
    __shared__ _Float16 smem[17408];          // As[8192] Bs[8192]; epi: Wt[128][136]
    __shared__ float rnI[128], rnJ[128];
    const int tid = threadIdx.x;
    const int lane = tid & 63, wv = tid >> 6;
    const int wr = wv >> 1, wc = wv & 1;
    const int m_ = lane & 15, quad = lane >> 4;
    const int rm = m_ & 7;
    const int b = blockIdx.z;

    // triangular tile pair (ti <= tj)
    int rem = blockIdx.x, ti = 0, rowlen = NN / 128;
    while (rem >= rowlen) { rem -= rowlen; ++ti; --rowlen; }
    const int tj = ti + rem;
    const int I = ti * 128, J = tj * 128;
    const bool diag = (ti == tj);

    const _Float16* Ab = xh + ((size_t)b * NN + I) * DD;
    const _Float16* Bb = xh + ((size_t)b * NN + J) * DD;
    if (tid < 128) rnI[tid] = rnorm[b * NN + I + tid];
    else           rnJ[tid - 128] = rnorm[b * NN + J + (tid - 128)];

    f32x4 acc[4][4];
    #pragma unroll
    for (int i = 0; i < 4; ++i)
        #pragma unroll
        for (int j = 0; j < 4; ++j) acc[i][j] = (f32x4){0.f, 0.f, 0.f, 0.f};

    _Float16* As = smem;
    _Float16* Bs = smem + 8192;

    // staging lane geometry: wave wv stages rows [wv*32, wv*32+32)
    const int sub = lane >> 3;                // row within 8-row group
    const int swc = (lane & 7) ^ sub;         // swizzled source chunk
    const _Float16* agl = Ab + (size_t)(wv * 32 + sub) * DD + swc * 8;
    const _Float16* bgl = Bb + (size_t)(wv * 32 + sub) * DD + swc * 8;

    for (int kb = 0; kb < DD / 64; ++kb) {
        const int k0 = kb * 64;
        #pragma unroll
        for (int c = 0; c < 4; ++c) {
            async_ld16(&As[(wv * 32 + c * 8) * 64], agl + (size_t)c * 8 * DD + k0);
            async_ld16(&Bs[(wv * 32 + c * 8) * 64], bgl + (size_t)c * 8 * DD + k0);
        }
        __syncthreads();
        #pragma unroll
        for (int kc = 0; kc < 2; ++kc) {
            f16x8 af[4], bf[4];
            #pragma unroll
            for (int t = 0; t < 4; ++t) {
                const int ko = ((kc * 4 + quad) ^ rm) * 8;
                af[t] = *(const f16x8*)&As[(wr * 64 + t * 16 + m_) * 64 + ko];
                bf[t] = *(const f16x8*)&Bs[(wc * 64 + t * 16 + m_) * 64 + ko];
            }
            #pragma unroll
            for (int i = 0; i < 4; ++i)
                #pragma unroll
                for (int j = 0; j < 4; ++j)
                    acc[i][j] = __builtin_amdgcn_mfma_f32_16x16x32_f16(af[i], bf[j], acc[i][j], 0, 0, 0);
        }
        __syncthreads();
    }

    // Epilogue: scale + exp -> Wt; register row/col partial sums.
    _Float16* Wt = smem;
    float rowpart[4][4];
    float colpart[4] = {0.f, 0.f, 0.f, 0.f};
    #pragma unroll
    for (int i = 0; i < 4; ++i)
        #pragma unroll
        for (int r = 0; r < 4; ++r) rowpart[i][r] = 0.f;

    #pragma unroll
    for (int i = 0; i < 4; ++i) {
        const int rowb = wr * 64 + i * 16 + quad * 4;
        #pragma unroll
        for (int j = 0; j < 4; ++j) {
            const int col = wc * 64 + j * 16 + m_;
            const float rj = rnJ[col];
            #pragma unroll
            for (int r = 0; r < 4; ++r) {
                const float w = __expf(acc[i][j][r] * rnI[rowb + r] * rj);
                Wt[(rowb + r) * 136 + col] = (_Float16)w;
                rowpart[i][r] += w;
                colpart[j] += w;
            }
        }
    }

    #pragma unroll
    for (int i = 0; i < 4; ++i) {
        #pragma unroll
        for (int r = 0; r < 4; ++r) {
            float s = rowpart[i][r];
            s += __shfl_xor(s, 1);
            s += __shfl_xor(s, 2);
            s += __shfl_xor(s, 4);
            s += __shfl_xor(s, 8);
            if (m_ == 0)
                atomicAdd(&denom[b * NN + I + wr * 64 + i * 16 + quad * 4 + r], s);
        }
    }
    if (!diag) {
        #pragma unroll
        for (int j = 0; j < 4; ++j) {
            float s = colpart[j];
            s += __shfl_xor(s, 16);
            s += __shfl_xor(s, 32);
            if (quad == 0)
                atomicAdd(&denom[b * NN + J + wc * 64 + j * 16 + m_], s);
        }
    }
    __syncthreads();

    // Coalesced store of W(I,J)
    {
        const int rr = tid >> 1, off = (tid & 1) * 64;
        _Float16* wg = W + ((size_t)b * NN + I + rr) * NN + J + off;
        const _Float16* wl = &Wt[rr * 136 + off];
        #pragma unroll
        for (int c = 0; c < 64; c += 8)
            *(uint4*)(wg + c) = *(const uint4*)(wl + c);
    }
    // Transposed store of W(J,I)
    if (!diag) {
        const int c = tid >> 1;
        const int h = tid & 1;
        _Float16* wg = W + ((size_t)b * NN + J + c) * NN + I + h * 64;
        #pragma unroll
        for (int g = 0; g < 8; ++g) {
            f16x8 v;
            #pragma unroll
            for (int k = 0; k < 8; ++k)
                v[k] = Wt[(h * 64 + g * 8 + k) * 136 + c];
            *(uint4*)(wg + g * 8) = *(const uint4*)&v;
        }
    }
}

// ---------------------------------------------------------------------------
// K3: O = (W @ V) * (1/denom_i), fp32 out. Same async-swizzled staging, K=2048.
// grid (N/128, D/128, B), 256 threads.
// ---------------------------------------------------------------------------
__global__ __launch_bounds__(256) void k_pv(const _Float16* __restrict__ W,
                                            const _Float16* __restrict__ vT,
                                            const float* __restrict__ denom,
                                            float* __restrict__ out) {
    __shared__ _Float16 smem[16384];          // As[8192] Bs[8192]
    __shared__ float rdI[128];
    const int tid = threadIdx.x;
    const int lane = tid & 63, wv = tid >> 6;
    const int wr = wv >> 1, wc = wv & 1;
    const int m_ = lane & 15, quad = lane >> 4;
    const int rm = m_ & 7;
    const int b = blockIdx.z;
    const int I = blockIdx.x * 128;
    const int D0 = blockIdx.y * 128;
    const _Float16* Ab = W + ((size_t)b * NN + I) * NN;
    const _Float16* Bb = vT + ((size_t)b * DD + D0) * NN;
    if (tid < 128) rdI[tid] = 1.0f / denom[b * NN + I + tid];

    f32x4 acc[4][4];
    #pragma unroll
    for (int i = 0; i < 4; ++i)
        #pragma unroll
        for (int j = 0; j < 4; ++j) acc[i][j] = (f32x4){0.f, 0.f, 0.f, 0.f};

    _Float16* As = smem;
    _Float16* Bs = smem + 8192;

    const int sub = lane >> 3;
    const int swc = (lane & 7) ^ sub;
    const _Float16* agl = Ab + (size_t)(wv * 32 + sub) * NN + swc * 8;
    const _Float16* bgl = Bb + (size_t)(wv * 32 + sub) * NN + swc * 8;

    for (int kb = 0; kb < NN / 64; ++kb) {
        const int k0 = kb * 64;
        #pragma unroll
        for (int c = 0; c < 4; ++c) {
            async_ld16(&As[(wv * 32 + c * 8) * 64], agl + (size_t)c * 8 * NN + k0);
            async_ld16(&Bs[(wv * 32 + c * 8) * 64], bgl + (size_t)c * 8 * NN + k0);
        }
        __syncthreads();
        #pragma unroll
        for (int kc = 0; kc < 2; ++kc) {
            f16x8 af[4], bf[4];
            #pragma unroll
            for (int t = 0; t < 4; ++t) {
                const int ko = ((kc * 4 + quad) ^ rm) * 8;
                af[t] = *(const f16x8*)&As[(wr * 64 + t * 16 + m_) * 64 + ko];
                bf[t] = *(const f16x8*)&Bs[(wc * 64 + t * 16 + m_) * 64 + ko];
            }
            #pragma unroll
            for (int i = 0; i < 4; ++i)
                #pragma unroll
                for (int j = 0; j < 4; ++j)
                    acc[i][j] = __builtin_amdgcn_mfma_f32_16x16x32_f16(af[i], bf[j], acc[i][j], 0, 0, 0);
        }
        __syncthreads();
    }

    #pragma unroll
    for (int i = 0; i < 4; ++i) {
        const int rowb = wr * 64 + i * 16 + quad * 4;
        #pragma unroll
        for (int r = 0; r < 4; ++r) {
            const float sc = rdI[rowb + r];
            float* op = out + ((size_t)b * NN + I + rowb + r) * DD + D0;
            #pragma unroll
            for (int j = 0; j < 4; ++j)
                op[wc * 64 + j * 16 + m_] = acc[i][j][r] * sc;
        }
    }
}

// ---------------------------------------------------------------------------
extern "C" void kernel_launch(void* const* d_in, const int* in_sizes, int n_in,
                              void* d_out, int out_size, void* d_ws, size_t ws_size,
                              hipStream_t stream) {
    const float* x = (const float*)d_in[0];
    char* ws = (char*)d_ws;
    _Float16* xh    = (_Float16*)(ws);                        // 32 MiB
    _Float16* vT    = (_Float16*)(ws + (size_t)33554432);     // 32 MiB
    _Float16* W     = (_Float16*)(ws + (size_t)67108864);     // 128 MiB
    float*    rnorm = (float*)   (ws + (size_t)201326592);    // 128 KiB
    float*    denom = (float*)   (ws + (size_t)201457664);    // 128 KiB
    float*    out   = (float*)d_out;

    k_prep_rows<<<BB * NN / 4, 256, 0, stream>>>(x, xh, rnorm, denom);
    k_transpose<<<dim3(NN / 64, DD / 64, BB), 256, 0, stream>>>(x, vT);
    const int npairs = (NN / 128) * (NN / 128 + 1) / 2;   // 136
    k_scores<<<dim3(npairs, 1, BB), 256, 0, stream>>>(xh, rnorm, W, denom);
    k_pv<<<dim3(NN / 128, DD / 128, BB), 256, 0, stream>>>(W, vT, denom, out);
}